// Round 1
// 333.030 us; speedup vs baseline: 1.0094x; 1.0094x over previous
//
#include <hip/hip_runtime.h>

typedef __attribute__((ext_vector_type(8))) short bf16x8;
typedef __attribute__((ext_vector_type(4))) float f32x4;

#define Hh   16
#define Ll   680
#define Cc   1024
#define Bb   16
#define NSEG 10
#define LPAD 720   // padded per-segment V length (each segment start 8-aligned)

__device__ __forceinline__ unsigned short f32_bf16(float f) {
  union { float f; unsigned int u; } x; x.f = f;
  unsigned int r = x.u + 0x7FFFu + ((x.u >> 16) & 1u);   // RNE
  return (unsigned short)(r >> 16);
}
__device__ __forceinline__ float bf16_f32(unsigned short u) {
  union { unsigned int u; float f; } x; x.u = ((unsigned int)u) << 16;
  return x.f;
}

__device__ __forceinline__ void async_copy16(const unsigned short* g, unsigned short* l) {
  __builtin_amdgcn_global_load_lds(
      (const __attribute__((address_space(1))) unsigned int*)g,
      (__attribute__((address_space(3))) unsigned int*)l, 16, 0, 0);
}

// segment tables (patch_nums are compile-time constants)
__device__ __constant__ int c_start2[11] = {0,1,5,14,30,55,91,155,255,424,680};
__device__ __constant__ int c_ps[NSEG]   = {0,8,16,32,48,80,120,184,288,464};
__device__ __constant__ int c_seg[16]    = {0,1,2,3,4,5,6,7,7,8,8,8,9,9,9,9};
__device__ __constant__ int c_tile0[16]  = {0,0,0,0,0,0,0,0,4,0,4,8,0,4,8,12};
__device__ __constant__ int c_len[NSEG]  = {1,4,9,16,25,36,64,100,169,256};

// compile-time l -> padded-l table (kills the per-element segment search)
struct PlTab { unsigned short v[Ll]; };
constexpr PlTab make_pl() {
  PlTab t{};
  int starts[11] = {0,1,5,14,30,55,91,155,255,424,680};
  int ps[10]     = {0,8,16,32,48,80,120,184,288,464};
  for (int s = 0; s < 10; ++s)
    for (int l = starts[s]; l < starts[s + 1]; ++l)
      t.v[l] = (unsigned short)(l - starts[s] + ps[s]);
  return t;
}
__device__ __constant__ PlTab c_plt = make_pl();

// ---------------- elementwise f32 -> bf16 cast ----------------
__global__ __launch_bounds__(256) void conv_kernel(const float* __restrict__ src,
                                                   unsigned short* __restrict__ dst, int n) {
  int i = (blockIdx.x * 256 + threadIdx.x) * 4;
  if (i + 3 < n) {
    float4 v = *reinterpret_cast<const float4*>(src + i);
    ushort4 o;
    o.x = f32_bf16(v.x); o.y = f32_bf16(v.y); o.z = f32_bf16(v.z); o.w = f32_bf16(v.w);
    *reinterpret_cast<ushort4*>(dst + i) = o;
  }
}

// ---------------- QKV GEMM v2: 128x256 tile, 8 waves, pipelined K-loop ----------------
// T3+T4+T5: 2 phases/K-tile, double-buffered 96KB LDS, counted vmcnt(6) at tile
// boundary (tile t+2 issued before waiting tile t+1 -> one full tile of latency cover).
// Per-wave output 64x64 (same fragment/swizzle algebra as verified 4-wave version).
// q -> (B,H,L,D) +bias ; k -> (B,H,L,D) l2-normalized ; v -> (B,H,D,LPAD) +bias, transposed.
__device__ __forceinline__ void stage_ab(const unsigned short* __restrict__ A,
                                         const unsigned short* __restrict__ Bm,
                                         unsigned short* __restrict__ As,
                                         unsigned short* __restrict__ Bs,
                                         int m0, int n0, int k0, int t, int wbase) {
  // A: 128 rows x 64 k -> 1024 chunks of 8 shorts; 2 loads/thread
#pragma unroll
  for (int i = 0; i < 2; ++i) {
    int c = i * 512 + t;
    int r = c >> 3;
    int part = (c & 7) ^ (r & 7);
    async_copy16(A + (size_t)(m0 + r) * 1024 + k0 + part * 8,
                 As + (size_t)(i * 512 + wbase) * 8);
  }
  // B: 256 rows x 64 k -> 2048 chunks; 4 loads/thread
#pragma unroll
  for (int i = 0; i < 4; ++i) {
    int c = i * 512 + t;
    int r = c >> 3;
    int part = (c & 7) ^ (r & 7);
    async_copy16(Bm + (size_t)(n0 + r) * 1024 + k0 + part * 8,
                 Bs + (size_t)(i * 512 + wbase) * 8);
  }
}

__global__ __launch_bounds__(512, 2) void gemm_qkv(const unsigned short* __restrict__ A,
                                                   const unsigned short* __restrict__ Bm,
                                                   const float* __restrict__ qb,
                                                   const float* __restrict__ vb,
                                                   unsigned short* __restrict__ qn,
                                                   unsigned short* __restrict__ kn,
                                                   unsigned short* __restrict__ vtb) {
  // per buffer: A = 1024 chunks (8192 shorts), B = 2048 chunks (16384 shorts) -> 48KB; x2 = 96KB
  __shared__ __align__(16) unsigned short lds[2][24576];
  const int t = threadIdx.x;
  const int lane = t & 63, w = t >> 6;
  const int col = lane & 15, quad = lane >> 4;
  const int wm = (w & 1) * 64, wn = (w >> 1) * 64;
  const int m0 = blockIdx.y * 128, n0 = blockIdx.x * 256;
  const int wbase = w * 64;

  f32x4 acc[4][4];
#pragma unroll
  for (int i = 0; i < 4; ++i)
#pragma unroll
    for (int j = 0; j < 4; ++j)
#pragma unroll
      for (int r = 0; r < 4; ++r) acc[i][j][r] = 0.f;

  // prologue: stage tiles 0 and 1; wait tile 0 only (tile 1 stays in flight)
  stage_ab(A, Bm, lds[0], lds[0] + 8192, m0, n0, 0, t, wbase);
  stage_ab(A, Bm, lds[1], lds[1] + 8192, m0, n0, 64, t, wbase);
  asm volatile("s_waitcnt vmcnt(6)" ::: "memory");
  __builtin_amdgcn_s_barrier();
  __builtin_amdgcn_sched_barrier(0);

  for (int tt = 0; tt < 16; ++tt) {
    unsigned short* As = lds[tt & 1];
    unsigned short* Bs = lds[tt & 1] + 8192;
    bf16x8 bf[4][2], af[2][2];

    // ---- phase 0: read all B frags + A frags (mi 0..1); 16 MFMA ----
#pragma unroll
    for (int ni = 0; ni < 4; ++ni) {
      int row = wn + ni * 16 + col;
#pragma unroll
      for (int kq = 0; kq < 2; ++kq)
        bf[ni][kq] = *reinterpret_cast<const bf16x8*>(
            &Bs[(row * 8 + ((kq * 4 + quad) ^ (col & 7))) * 8]);
    }
#pragma unroll
    for (int mi = 0; mi < 2; ++mi) {
      int row = wm + mi * 16 + col;
#pragma unroll
      for (int kq = 0; kq < 2; ++kq)
        af[mi][kq] = *reinterpret_cast<const bf16x8*>(
            &As[(row * 8 + ((kq * 4 + quad) ^ (col & 7))) * 8]);
    }
    __builtin_amdgcn_s_setprio(1);
#pragma unroll
    for (int mi = 0; mi < 2; ++mi)
#pragma unroll
      for (int ni = 0; ni < 4; ++ni)
#pragma unroll
        for (int kq = 0; kq < 2; ++kq)
          acc[mi][ni] = __builtin_amdgcn_mfma_f32_16x16x32_bf16(af[mi][kq], bf[ni][kq],
                                                                acc[mi][ni], 0, 0, 0);
    __builtin_amdgcn_s_setprio(0);
    __builtin_amdgcn_s_barrier();

    // ---- phase 1: read A frags (mi 2..3), reuse B; 16 MFMA ----
#pragma unroll
    for (int mi = 0; mi < 2; ++mi) {
      int row = wm + (2 + mi) * 16 + col;
#pragma unroll
      for (int kq = 0; kq < 2; ++kq)
        af[mi][kq] = *reinterpret_cast<const bf16x8*>(
            &As[(row * 8 + ((kq * 4 + quad) ^ (col & 7))) * 8]);
    }
    __builtin_amdgcn_s_setprio(1);
#pragma unroll
    for (int mi = 0; mi < 2; ++mi)
#pragma unroll
      for (int ni = 0; ni < 4; ++ni)
#pragma unroll
        for (int kq = 0; kq < 2; ++kq)
          acc[2 + mi][ni] = __builtin_amdgcn_mfma_f32_16x16x32_bf16(af[mi][kq], bf[ni][kq],
                                                                    acc[2 + mi][ni], 0, 0, 0);
    __builtin_amdgcn_s_setprio(0);
    __builtin_amdgcn_s_barrier();   // all waves done reading buf[tt&1]

    // ---- tile boundary: stage t+2 into just-freed buffer, wait only t+1 ----
    if (tt < 14) {
      stage_ab(A, Bm, lds[tt & 1], lds[tt & 1] + 8192, m0, n0, (tt + 2) * 64, t, wbase);
      asm volatile("s_waitcnt vmcnt(6)" ::: "memory");   // t+1 landed; t+2 in flight
      __builtin_amdgcn_s_barrier();
      __builtin_amdgcn_sched_barrier(0);
    } else if (tt == 14) {
      asm volatile("s_waitcnt vmcnt(0)" ::: "memory");   // last tile: drain
      __builtin_amdgcn_s_barrier();
      __builtin_amdgcn_sched_barrier(0);
    }
  }

  // ---- fused epilogue (same algebra as verified version; wave owns one head) ----
  const int nbase = n0 + wn;
  const int field = nbase >> 10;          // wave-uniform
  const int h = (nbase >> 6) & 15;

  if (field < 2) {
    float scl[4][4];
    if (field == 1) {                     // k: per-row 1/||k|| across the 16 col-lanes
#pragma unroll
      for (int mi = 0; mi < 4; ++mi)
#pragma unroll
        for (int r = 0; r < 4; ++r) {
          float s = 0.f;
#pragma unroll
          for (int ni = 0; ni < 4; ++ni) s += acc[mi][ni][r] * acc[mi][ni][r];
          s += __shfl_xor(s, 1); s += __shfl_xor(s, 2);
          s += __shfl_xor(s, 4); s += __shfl_xor(s, 8);
          scl[mi][r] = 1.f / fmaxf(sqrtf(s), 1e-12f);
        }
    }
    unsigned short* dst0 = (field == 0) ? qn : kn;
#pragma unroll
    for (int ni = 0; ni < 4; ++ni) {
      const int d = ni * 16 + col;
      const float bv = (field == 0) ? qb[h * 64 + d] : 0.f;
#pragma unroll
      for (int mi = 0; mi < 4; ++mi)
#pragma unroll
        for (int r = 0; r < 4; ++r) {
          int gm = m0 + wm + mi * 16 + quad * 4 + r;
          int b = gm / 680, l = gm - b * 680;
          float v = (field == 0) ? (acc[mi][ni][r] + bv) : (acc[mi][ni][r] * scl[mi][r]);
          dst0[((size_t)(b * Hh + h) * Ll + l) * 64 + d] = f32_bf16(v);
        }
    }
  } else {                                // v: transposed, segment-padded (table lookup)
#pragma unroll
    for (int mi = 0; mi < 4; ++mi) {
      int pl4[4], bb4[4];
#pragma unroll
      for (int r = 0; r < 4; ++r) {
        int gm = m0 + wm + mi * 16 + quad * 4 + r;
        int b = gm / 680, l = gm - b * 680;
        pl4[r] = c_plt.v[l];
        bb4[r] = b;
      }
#pragma unroll
      for (int ni = 0; ni < 4; ++ni) {
        const int d = ni * 16 + col;
        const float bv = vb[h * 64 + d];
#pragma unroll
        for (int r = 0; r < 4; ++r)
          vtb[((size_t)(bb4[r] * Hh + h) * 64 + d) * LPAD + pl4[r]] =
              f32_bf16(acc[mi][ni][r] + bv);
      }
    }
  }
}

// ---------------- plain B^T GEMM (proj), f32 out ----------------
__global__ __launch_bounds__(256) void gemm_bt(const unsigned short* __restrict__ A,
                                               const unsigned short* __restrict__ Bm,
                                               const float* __restrict__ bias,
                                               float* __restrict__ outp,
                                               int M, int N, int K) {
  __shared__ __align__(16) unsigned short As[128 * 64];
  __shared__ __align__(16) unsigned short Bs[128 * 64];
  const int t = threadIdx.x;
  const int lane = t & 63, w = t >> 6;
  const int col = lane & 15, quad = lane >> 4;
  const int wm = (w & 1) * 64, wn = (w >> 1) * 64;
  const int m0 = blockIdx.y * 128, n0 = blockIdx.x * 128;

  f32x4 acc[4][4];
#pragma unroll
  for (int i = 0; i < 4; ++i)
#pragma unroll
    for (int j = 0; j < 4; ++j)
#pragma unroll
      for (int r = 0; r < 4; ++r) acc[i][j][r] = 0.f;

  const int cbase = w * 256 + lane;
  for (int k0 = 0; k0 < K; k0 += 64) {
    __syncthreads();
#pragma unroll
    for (int i = 0; i < 4; ++i) {
      int c = cbase + i * 64;
      int r = c >> 3;
      int part = (c & 7) ^ (r & 7);
      async_copy16(A + (size_t)(m0 + r) * K + k0 + part * 8, As + (w * 256 + i * 64) * 8);
      async_copy16(Bm + (size_t)(n0 + r) * K + k0 + part * 8, Bs + (w * 256 + i * 64) * 8);
    }
    __syncthreads();
#pragma unroll
    for (int kk = 0; kk < 64; kk += 32) {
      const int p = (kk >> 3) + quad;
      bf16x8 af[4], bfr[4];
#pragma unroll
      for (int mi = 0; mi < 4; ++mi) {
        int row = wm + mi * 16 + col;
        af[mi] = *reinterpret_cast<const bf16x8*>(&As[(row * 8 + (p ^ (col & 7))) * 8]);
      }
#pragma unroll
      for (int ni = 0; ni < 4; ++ni) {
        int row = wn + ni * 16 + col;
        bfr[ni] = *reinterpret_cast<const bf16x8*>(&Bs[(row * 8 + (p ^ (col & 7))) * 8]);
      }
#pragma unroll
      for (int mi = 0; mi < 4; ++mi)
#pragma unroll
        for (int ni = 0; ni < 4; ++ni)
          acc[mi][ni] = __builtin_amdgcn_mfma_f32_16x16x32_bf16(af[mi], bfr[ni], acc[mi][ni], 0, 0, 0);
    }
  }
#pragma unroll
  for (int mi = 0; mi < 4; ++mi)
#pragma unroll
    for (int ni = 0; ni < 4; ++ni) {
      int gn = n0 + wn + ni * 16 + col;
      float bv = bias[gn];
#pragma unroll
      for (int r = 0; r < 4; ++r) {
        int gm = m0 + wm + mi * 16 + quad * 4 + r;
        outp[(size_t)gm * N + gn] = acc[mi][ni][r] + bv;
      }
    }
}

// ---------------- attention v5: sized staging + XCD-grouped slots ----------------
// blockIdx = wi*256 + bh  ->  all 16 slots of one (b,h) share blockIdx%8 (same XCD L2).
// Staging sized to the segment: K stages jtc*16 rows; V stages jtcp*2 j-chunks per d.
__global__ __launch_bounds__(256) void attn_kernel(const unsigned short* __restrict__ qn,
                                                   const unsigned short* __restrict__ kn,
                                                   const unsigned short* __restrict__ vtb,
                                                   const float* __restrict__ slog,
                                                   unsigned short* __restrict__ outb) {
  __shared__ __align__(16) unsigned short Ks[128 * 64];   // chunk(row,cc) at row*8 + (cc^(row&7))
  __shared__ __align__(16) unsigned short Vs[64 * 128];   // chunk(d,jc)  at d*16 + (jc^(d&15))
  __shared__ __align__(16) unsigned short Ps[4 * 16 * 132];

  const int t = threadIdx.x;
  const int lane = t & 63, w = t >> 6;
  const int col = lane & 15, quad = lane >> 4;
  const int wi = blockIdx.x >> 8, bh = blockIdx.x & 255;
  const int h = bh & 15;
  const int seg = c_seg[wi];
  const int start = c_start2[seg], ln = c_len[seg], ps = c_ps[seg];
  const int njt = (ln + 15) >> 4;
  const int nchunk = (njt + 7) >> 3;
  const int qt = c_tile0[wi] + w;
  const bool qvalid = qt < njt;
  const float smul = __expf(fminf(slog[h], 4.6051701859880914f));

  // ---- Q fragment + in-register l2norm*scale ----
  const int qi = qt * 16 + col;
  const unsigned short* qrow = qn + ((size_t)bh * Ll + start + qi) * 64;
  bf16x8 qf0 = *reinterpret_cast<const bf16x8*>(qrow + quad * 8);
  bf16x8 qf1 = *reinterpret_cast<const bf16x8*>(qrow + 32 + quad * 8);
  {
    float ss = 0.f;
#pragma unroll
    for (int e = 0; e < 8; ++e) {
      float f0 = bf16_f32((unsigned short)qf0[e]), f1 = bf16_f32((unsigned short)qf1[e]);
      ss += f0 * f0 + f1 * f1;
    }
    ss += __shfl_xor(ss, 16);
    ss += __shfl_xor(ss, 32);
    const float qsc = smul / fmaxf(sqrtf(ss), 1e-12f);
#pragma unroll
    for (int e = 0; e < 8; ++e) {
      qf0[e] = (short)f32_bf16(bf16_f32((unsigned short)qf0[e]) * qsc);
      qf1[e] = (short)f32_bf16(bf16_f32((unsigned short)qf1[e]) * qsc);
    }
  }

  f32x4 o[4];
#pragma unroll
  for (int nt = 0; nt < 4; ++nt)
#pragma unroll
    for (int r = 0; r < 4; ++r) o[nt][r] = 0.f;
  float m4[4] = {-1e30f, -1e30f, -1e30f, -1e30f};
  float l4[4] = {0.f, 0.f, 0.f, 0.f};

  const int jc_t = (t & 15) ^ (t >> 4);   // thread-fixed V j-chunk

  for (int ch = 0; ch < nchunk; ++ch) {
    const int jbase = ch * 128;
    const int jtc = (njt - ch * 8 > 8) ? 8 : (njt - ch * 8);
    const int jtcp = (jtc + 1) & ~1;
    const int rowsK = jtc * 16;
    const int jcmax = jtcp * 2;
    __syncthreads();   // previous chunk's LDS reads done

    // ---- stage K rows (rowsK x 64d): chunk grid 128x8, rows >= rowsK skipped ----
#pragma unroll
    for (int i = 0; i < 4; ++i) {
      int c = i * 256 + w * 64 + lane;
      int jr = c >> 3;
      if (jr < rowsK) {
        int cc = (c & 7) ^ (jr & 7);
        async_copy16(kn + ((size_t)bh * Ll + start + jbase + jr) * 64 + cc * 8,
                     Ks + (i * 256 + w * 64) * 8);
      }
    }
    // ---- stage V^T (64d x jcmax*8 j): chunk grid 64x16, jc >= jcmax skipped ----
    if (jc_t < jcmax) {
#pragma unroll
      for (int i = 0; i < 4; ++i) {
        int d = i * 16 + (t >> 4);
        async_copy16(vtb + ((size_t)bh * 64 + d) * LPAD + ps + jbase + jc_t * 8,
                     Vs + (i * 256 + w * 64) * 8);
      }
    }
    __syncthreads();

    // ---- S = Q K^T ----
    f32x4 sf[8];
#pragma unroll
    for (int jt = 0; jt < 8; ++jt) {
      if (jt >= jtcp) continue;
      f32x4 s;
#pragma unroll
      for (int r = 0; r < 4; ++r) s[r] = 0.f;
      if (jt < jtc) {
        int jrow = jt * 16 + col;
        bf16x8 k0 = *reinterpret_cast<const bf16x8*>(&Ks[(jrow * 8 + (quad ^ (jrow & 7))) * 8]);
        bf16x8 k1 = *reinterpret_cast<const bf16x8*>(&Ks[(jrow * 8 + ((4 + quad) ^ (jrow & 7))) * 8]);
        s = __builtin_amdgcn_mfma_f32_16x16x32_bf16(qf0, k0, s, 0, 0, 0);
        s = __builtin_amdgcn_mfma_f32_16x16x32_bf16(qf1, k1, s, 0, 0, 0);
      }
      if (jbase + jt * 16 + col >= ln) {
#pragma unroll
        for (int r = 0; r < 4; ++r) s[r] = -1e30f;
      }
      sf[jt] = s;
    }
    // ---- online softmax ----
    float mc[4];
#pragma unroll
    for (int r = 0; r < 4; ++r) mc[r] = sf[0][r];
#pragma unroll
    for (int jt = 1; jt < 8; ++jt) {
      if (jt >= jtcp) continue;
#pragma unroll
      for (int r = 0; r < 4; ++r) mc[r] = fmaxf(mc[r], sf[jt][r]);
    }
#pragma unroll
    for (int mask = 1; mask <= 8; mask <<= 1)
#pragma unroll
      for (int r = 0; r < 4; ++r) mc[r] = fmaxf(mc[r], __shfl_xor(mc[r], mask));
    float alpha[4];
#pragma unroll
    for (int r = 0; r < 4; ++r) {
      float mn = fmaxf(m4[r], mc[r]);
      alpha[r] = __expf(m4[r] - mn);
      m4[r] = mn;
    }
    float ls[4] = {0.f, 0.f, 0.f, 0.f};
#pragma unroll
    for (int jt = 0; jt < 8; ++jt) {
      if (jt >= jtcp) continue;
#pragma unroll
      for (int r = 0; r < 4; ++r) {
        float pv = __expf(sf[jt][r] - m4[r]);
        ls[r] += pv;
        Ps[(w * 16 + quad * 4 + r) * 132 + jt * 16 + col] = f32_bf16(pv);
      }
    }
#pragma unroll
    for (int mask = 1; mask <= 8; mask <<= 1)
#pragma unroll
      for (int r = 0; r < 4; ++r) ls[r] += __shfl_xor(ls[r], mask);
#pragma unroll
    for (int r = 0; r < 4; ++r) l4[r] = l4[r] * alpha[r] + ls[r];
#pragma unroll
    for (int nt = 0; nt < 4; ++nt)
#pragma unroll
      for (int r = 0; r < 4; ++r) o[nt][r] *= alpha[r];

    // ---- O += P V ----
#pragma unroll
    for (int kk2 = 0; kk2 < 4; ++kk2) {
      if (kk2 >= (jtcp >> 1)) continue;
      bf16x8 pf = *reinterpret_cast<const bf16x8*>(&Ps[(w * 16 + col) * 132 + kk2 * 32 + quad * 8]);
#pragma unroll
      for (int nt = 0; nt < 4; ++nt) {
        int d = nt * 16 + col;
        int slot = (kk2 * 4 + quad) ^ (d & 15);
        bf16x8 vf = *reinterpret_cast<const bf16x8*>(&Vs[(d * 16 + slot) * 8]);
        o[nt] = __builtin_amdgcn_mfma_f32_16x16x32_bf16(pf, vf, o[nt], 0, 0, 0);
      }
    }
  }

  if (qvalid) {
    float inv[4];
#pragma unroll
    for (int r = 0; r < 4; ++r) inv[r] = 1.f / l4[r];
    const int b = bh >> 4;
#pragma unroll
    for (int nt = 0; nt < 4; ++nt)
#pragma unroll
      for (int r = 0; r < 4; ++r) {
        int ri = qt * 16 + quad * 4 + r;
        if (ri < ln) {
          size_t off = ((size_t)b * Ll + start + ri) * Cc + h * 64 + nt * 16 + col;
          outb[off] = f32_bf16(o[nt][r] * inv[r]);
        }
      }
  }
}

extern "C" void kernel_launch(void* const* d_in, const int* in_sizes, int n_in,
                              void* d_out, int out_size, void* d_ws, size_t ws_size,
                              hipStream_t stream) {
  const float* x     = (const float*)d_in[0];
  const float* wqkv  = (const float*)d_in[2];
  const float* qbias = (const float*)d_in[3];
  const float* vbias = (const float*)d_in[4];
  const float* slog  = (const float*)d_in[5];
  const float* wproj = (const float*)d_in[6];
  const float* pbias = (const float*)d_in[7];
  float* out = (float*)d_out;

  const size_t nX  = (size_t)Bb * Ll * Cc;      // 11,141,120
  const size_t nWq = (size_t)3 * Cc * Cc;       // 3,145,728
  const size_t nWp = (size_t)Cc * Cc;           // 1,048,576
  const size_t nVt = (size_t)Bb * Hh * 64 * LPAD;

  char* p = (char*)d_ws;
  unsigned short* xb     = (unsigned short*)p;  p += nX * 2;
  unsigned short* wqkvb  = (unsigned short*)p;  p += nWq * 2;
  unsigned short* wprojb = (unsigned short*)p;  p += nWp * 2;
  unsigned short* qn     = (unsigned short*)p;  p += nX * 2;
  unsigned short* kn     = (unsigned short*)p;  p += nX * 2;
  unsigned short* vtb    = (unsigned short*)p;  p += nVt * 2;
  unsigned short* attn   = xb;  // reuse: xb dead after gemm_qkv

  conv_kernel<<<(int)(nX / 1024), 256, 0, stream>>>(x, xb, (int)nX);
  conv_kernel<<<(int)(nWq / 1024), 256, 0, stream>>>(wqkv, wqkvb, (int)nWq);
  conv_kernel<<<(int)(nWp / 1024), 256, 0, stream>>>(wproj, wprojb, (int)nWp);

  gemm_qkv<<<dim3(12, 85), 512, 0, stream>>>(xb, wqkvb, qbias, vbias, qn, kn, vtb);
  attn_kernel<<<Bb * Hh * 16, 256, 0, stream>>>(qn, kn, vtb, slog, attn);
  gemm_bt<<<dim3(8, 85), 256, 0, stream>>>(attn, wprojb, pbias, out, 10880, 1024, 1024);
}

// Round 3
// 330.216 us; speedup vs baseline: 1.0180x; 1.0085x over previous
//
#include <hip/hip_runtime.h>

typedef __attribute__((ext_vector_type(8))) short bf16x8;
typedef __attribute__((ext_vector_type(4))) float f32x4;

#define Hh   16
#define Ll   680
#define Cc   1024
#define Bb   16
#define NSEG 10
#define LPAD 720   // padded per-segment V length (each segment start 8-aligned)

__device__ __forceinline__ unsigned short f32_bf16(float f) {
  union { float f; unsigned int u; } x; x.f = f;
  unsigned int r = x.u + 0x7FFFu + ((x.u >> 16) & 1u);   // RNE
  return (unsigned short)(r >> 16);
}
__device__ __forceinline__ float bf16_f32(unsigned short u) {
  union { unsigned int u; float f; } x; x.u = ((unsigned int)u) << 16;
  return x.f;
}

__device__ __forceinline__ void async_copy16(const unsigned short* g, unsigned short* l) {
  __builtin_amdgcn_global_load_lds(
      (const __attribute__((address_space(1))) unsigned int*)g,
      (__attribute__((address_space(3))) unsigned int*)l, 16, 0, 0);
}

// segment tables (patch_nums are compile-time constants)
__device__ __constant__ int c_start2[11] = {0,1,5,14,30,55,91,155,255,424,680};
__device__ __constant__ int c_ps[NSEG]   = {0,8,16,32,48,80,120,184,288,464};
__device__ __constant__ int c_seg[16]    = {0,1,2,3,4,5,6,7,7,8,8,8,9,9,9,9};
__device__ __constant__ int c_tile0[16]  = {0,0,0,0,0,0,0,0,4,0,4,8,0,4,8,12};
__device__ __constant__ int c_len[NSEG]  = {1,4,9,16,25,36,64,100,169,256};

// compile-time l -> padded-l table (kills the per-element segment search)
struct PlTab { unsigned short v[Ll]; };
constexpr PlTab make_pl() {
  PlTab t{};
  int starts[11] = {0,1,5,14,30,55,91,155,255,424,680};
  int ps[10]     = {0,8,16,32,48,80,120,184,288,464};
  for (int s = 0; s < 10; ++s)
    for (int l = starts[s]; l < starts[s + 1]; ++l)
      t.v[l] = (unsigned short)(l - starts[s] + ps[s]);
  return t;
}
__device__ __constant__ PlTab c_plt = make_pl();

// ---------------- elementwise f32 -> bf16 cast ----------------
__global__ __launch_bounds__(256) void conv_kernel(const float* __restrict__ src,
                                                   unsigned short* __restrict__ dst, int n) {
  int i = (blockIdx.x * 256 + threadIdx.x) * 4;
  if (i + 3 < n) {
    float4 v = *reinterpret_cast<const float4*>(src + i);
    ushort4 o;
    o.x = f32_bf16(v.x); o.y = f32_bf16(v.y); o.z = f32_bf16(v.z); o.w = f32_bf16(v.w);
    *reinterpret_cast<ushort4*>(dst + i) = o;
  }
}

// ---------------- QKV GEMM v3: 128x256 tile, 8 waves, triple-buffered, XCD-chunked ----------------
// T1: bijective XCD-chunk swizzle (nwg=1020) so the ~32 blocks resident on one XCD are
// n-fast consecutive -> A panels shared within one L2, B slices reused x2.7.
// T3+T4: 3-deep pipeline (144KB LDS), boundary wait vmcnt(12) -> 2 tiles of latency cover.
// Per-wave output 64x64 (same fragment/swizzle algebra as verified version).
__device__ __forceinline__ void stage_ab(const unsigned short* __restrict__ A,
                                         const unsigned short* __restrict__ Bm,
                                         unsigned short* __restrict__ As,
                                         unsigned short* __restrict__ Bs,
                                         int m0, int n0, int k0, int t, int wbase) {
  // A: 128 rows x 64 k -> 1024 chunks of 8 shorts; 2 loads/thread
#pragma unroll
  for (int i = 0; i < 2; ++i) {
    int c = i * 512 + t;
    int r = c >> 3;
    int part = (c & 7) ^ (r & 7);
    async_copy16(A + (size_t)(m0 + r) * 1024 + k0 + part * 8,
                 As + (size_t)(i * 512 + wbase) * 8);
  }
  // B: 256 rows x 64 k -> 2048 chunks; 4 loads/thread
#pragma unroll
  for (int i = 0; i < 4; ++i) {
    int c = i * 512 + t;
    int r = c >> 3;
    int part = (c & 7) ^ (r & 7);
    async_copy16(Bm + (size_t)(n0 + r) * 1024 + k0 + part * 8,
                 Bs + (size_t)(i * 512 + wbase) * 8);
  }
}

__global__ __launch_bounds__(512, 2) void gemm_qkv(const unsigned short* __restrict__ A,
                                                   const unsigned short* __restrict__ Bm,
                                                   const float* __restrict__ qb,
                                                   const float* __restrict__ vb,
                                                   unsigned short* __restrict__ qn,
                                                   unsigned short* __restrict__ kn,
                                                   unsigned short* __restrict__ vtb) {
  // per buffer: A = 1024 chunks (8192 shorts), B = 2048 chunks (16384 shorts) -> 48KB; x3 = 144KB
  __shared__ __align__(16) unsigned short lds[3][24576];
  const int t = threadIdx.x;
  const int lane = t & 63, w = t >> 6;
  const int col = lane & 15, quad = lane >> 4;
  const int wm = (w & 1) * 64, wn = (w >> 1) * 64;

  // bijective XCD-chunk swizzle: nwg = 1020 = 8*127 + 4
  const int id = blockIdx.y * 12 + blockIdx.x;       // HW dispatch order (x fastest)
  const int xcd = id & 7, pos = id >> 3;
  const int rid = (xcd < 4 ? xcd * 128 : 512 + (xcd - 4) * 127) + pos;
  const int m0 = (rid / 12) * 128, n0 = (rid % 12) * 256;
  const int wbase = w * 64;

  f32x4 acc[4][4];
#pragma unroll
  for (int i = 0; i < 4; ++i)
#pragma unroll
    for (int j = 0; j < 4; ++j)
#pragma unroll
      for (int r = 0; r < 4; ++r) acc[i][j][r] = 0.f;

  // prologue: stage tiles 0,1,2; wait tile 0 only (1,2 stay in flight)
  stage_ab(A, Bm, lds[0], lds[0] + 8192, m0, n0, 0, t, wbase);
  stage_ab(A, Bm, lds[1], lds[1] + 8192, m0, n0, 64, t, wbase);
  stage_ab(A, Bm, lds[2], lds[2] + 8192, m0, n0, 128, t, wbase);
  asm volatile("s_waitcnt vmcnt(12)" ::: "memory");
  __builtin_amdgcn_s_barrier();
  __builtin_amdgcn_sched_barrier(0);

  int bsel = 0;
  for (int tt = 0; tt < 16; ++tt) {
    unsigned short* As = lds[bsel];
    unsigned short* Bs = lds[bsel] + 8192;
    bf16x8 bf[4][2], af[2][2];

    // ---- phase 0: read all B frags + A frags (mi 0..1); 16 MFMA ----
#pragma unroll
    for (int ni = 0; ni < 4; ++ni) {
      int row = wn + ni * 16 + col;
#pragma unroll
      for (int kq = 0; kq < 2; ++kq)
        bf[ni][kq] = *reinterpret_cast<const bf16x8*>(
            &Bs[(row * 8 + ((kq * 4 + quad) ^ (col & 7))) * 8]);
    }
#pragma unroll
    for (int mi = 0; mi < 2; ++mi) {
      int row = wm + mi * 16 + col;
#pragma unroll
      for (int kq = 0; kq < 2; ++kq)
        af[mi][kq] = *reinterpret_cast<const bf16x8*>(
            &As[(row * 8 + ((kq * 4 + quad) ^ (col & 7))) * 8]);
    }
    __builtin_amdgcn_s_setprio(1);
#pragma unroll
    for (int mi = 0; mi < 2; ++mi)
#pragma unroll
      for (int ni = 0; ni < 4; ++ni)
#pragma unroll
        for (int kq = 0; kq < 2; ++kq)
          acc[mi][ni] = __builtin_amdgcn_mfma_f32_16x16x32_bf16(af[mi][kq], bf[ni][kq],
                                                                acc[mi][ni], 0, 0, 0);
    __builtin_amdgcn_s_setprio(0);
    __builtin_amdgcn_s_barrier();

    // ---- phase 1: read A frags (mi 2..3), reuse B; 16 MFMA ----
#pragma unroll
    for (int mi = 0; mi < 2; ++mi) {
      int row = wm + (2 + mi) * 16 + col;
#pragma unroll
      for (int kq = 0; kq < 2; ++kq)
        af[mi][kq] = *reinterpret_cast<const bf16x8*>(
            &As[(row * 8 + ((kq * 4 + quad) ^ (col & 7))) * 8]);
    }
    __builtin_amdgcn_s_setprio(1);
#pragma unroll
    for (int mi = 0; mi < 2; ++mi)
#pragma unroll
      for (int ni = 0; ni < 4; ++ni)
#pragma unroll
        for (int kq = 0; kq < 2; ++kq)
          acc[2 + mi][ni] = __builtin_amdgcn_mfma_f32_16x16x32_bf16(af[mi][kq], bf[ni][kq],
                                                                    acc[2 + mi][ni], 0, 0, 0);
    __builtin_amdgcn_s_setprio(0);
    __builtin_amdgcn_s_barrier();   // all waves done reading buf[bsel]

    // ---- tile boundary: stage t+3 into just-freed buffer; wait only t+1 ----
    if (tt <= 12) {
      stage_ab(A, Bm, lds[bsel], lds[bsel] + 8192, m0, n0, (tt + 3) * 64, t, wbase);
      asm volatile("s_waitcnt vmcnt(12)" ::: "memory");   // t+1 landed; t+2,t+3 in flight
      __builtin_amdgcn_s_barrier();
      __builtin_amdgcn_sched_barrier(0);
    } else if (tt == 13) {
      asm volatile("s_waitcnt vmcnt(6)" ::: "memory");    // t14 landed; t15 in flight
      __builtin_amdgcn_s_barrier();
      __builtin_amdgcn_sched_barrier(0);
    } else if (tt == 14) {
      asm volatile("s_waitcnt vmcnt(0)" ::: "memory");    // t15 landed
      __builtin_amdgcn_s_barrier();
      __builtin_amdgcn_sched_barrier(0);
    }
    bsel = (bsel == 2) ? 0 : bsel + 1;
  }

  // ---- fused epilogue (same algebra as verified version; wave owns one head) ----
  const int nbase = n0 + wn;
  const int field = nbase >> 10;          // wave-uniform
  const int h = (nbase >> 6) & 15;

  if (field < 2) {
    float scl[4][4];
    if (field == 1) {                     // k: per-row 1/||k|| across the 16 col-lanes
#pragma unroll
      for (int mi = 0; mi < 4; ++mi)
#pragma unroll
        for (int r = 0; r < 4; ++r) {
          float s = 0.f;
#pragma unroll
          for (int ni = 0; ni < 4; ++ni) s += acc[mi][ni][r] * acc[mi][ni][r];
          s += __shfl_xor(s, 1); s += __shfl_xor(s, 2);
          s += __shfl_xor(s, 4); s += __shfl_xor(s, 8);
          scl[mi][r] = 1.f / fmaxf(sqrtf(s), 1e-12f);
        }
    }
    unsigned short* dst0 = (field == 0) ? qn : kn;
#pragma unroll
    for (int ni = 0; ni < 4; ++ni) {
      const int d = ni * 16 + col;
      const float bv = (field == 0) ? qb[h * 64 + d] : 0.f;
#pragma unroll
      for (int mi = 0; mi < 4; ++mi)
#pragma unroll
        for (int r = 0; r < 4; ++r) {
          int gm = m0 + wm + mi * 16 + quad * 4 + r;
          int b = gm / 680, l = gm - b * 680;
          float v = (field == 0) ? (acc[mi][ni][r] + bv) : (acc[mi][ni][r] * scl[mi][r]);
          dst0[((size_t)(b * Hh + h) * Ll + l) * 64 + d] = f32_bf16(v);
        }
    }
  } else {                                // v: transposed, segment-padded (table lookup)
#pragma unroll
    for (int mi = 0; mi < 4; ++mi) {
      int pl4[4], bb4[4];
#pragma unroll
      for (int r = 0; r < 4; ++r) {
        int gm = m0 + wm + mi * 16 + quad * 4 + r;
        int b = gm / 680, l = gm - b * 680;
        pl4[r] = c_plt.v[l];
        bb4[r] = b;
      }
#pragma unroll
      for (int ni = 0; ni < 4; ++ni) {
        const int d = ni * 16 + col;
        const float bv = vb[h * 64 + d];
#pragma unroll
        for (int r = 0; r < 4; ++r)
          vtb[((size_t)(bb4[r] * Hh + h) * 64 + d) * LPAD + pl4[r]] =
              f32_bf16(acc[mi][ni][r] + bv);
      }
    }
  }
}

// ---------------- plain B^T GEMM (proj), f32 out, XCD-chunked ----------------
__global__ __launch_bounds__(256) void gemm_bt(const unsigned short* __restrict__ A,
                                               const unsigned short* __restrict__ Bm,
                                               const float* __restrict__ bias,
                                               float* __restrict__ outp,
                                               int M, int N, int K) {
  __shared__ __align__(16) unsigned short As[128 * 64];
  __shared__ __align__(16) unsigned short Bs[128 * 64];
  const int t = threadIdx.x;
  const int lane = t & 63, w = t >> 6;
  const int col = lane & 15, quad = lane >> 4;
  const int wm = (w & 1) * 64, wn = (w >> 1) * 64;

  // XCD-chunk swizzle: nwg = 680 = 8*85 (exact)
  const int id = blockIdx.y * 8 + blockIdx.x;
  const int rid = (id & 7) * 85 + (id >> 3);
  const int m0 = (rid >> 3) * 128, n0 = (rid & 7) * 128;

  f32x4 acc[4][4];
#pragma unroll
  for (int i = 0; i < 4; ++i)
#pragma unroll
    for (int j = 0; j < 4; ++j)
#pragma unroll
      for (int r = 0; r < 4; ++r) acc[i][j][r] = 0.f;

  const int cbase = w * 256 + lane;
  for (int k0 = 0; k0 < K; k0 += 64) {
    __syncthreads();
#pragma unroll
    for (int i = 0; i < 4; ++i) {
      int c = cbase + i * 64;
      int r = c >> 3;
      int part = (c & 7) ^ (r & 7);
      async_copy16(A + (size_t)(m0 + r) * K + k0 + part * 8, As + (w * 256 + i * 64) * 8);
      async_copy16(Bm + (size_t)(n0 + r) * K + k0 + part * 8, Bs + (w * 256 + i * 64) * 8);
    }
    __syncthreads();
#pragma unroll
    for (int kk = 0; kk < 64; kk += 32) {
      const int p = (kk >> 3) + quad;
      bf16x8 af[4], bfr[4];
#pragma unroll
      for (int mi = 0; mi < 4; ++mi) {
        int row = wm + mi * 16 + col;
        af[mi] = *reinterpret_cast<const bf16x8*>(&As[(row * 8 + (p ^ (col & 7))) * 8]);
      }
#pragma unroll
      for (int ni = 0; ni < 4; ++ni) {
        int row = wn + ni * 16 + col;
        bfr[ni] = *reinterpret_cast<const bf16x8*>(&Bs[(row * 8 + (p ^ (col & 7))) * 8]);
      }
#pragma unroll
      for (int mi = 0; mi < 4; ++mi)
#pragma unroll
        for (int ni = 0; ni < 4; ++ni)
          acc[mi][ni] = __builtin_amdgcn_mfma_f32_16x16x32_bf16(af[mi], bfr[ni], acc[mi][ni], 0, 0, 0);
    }
  }
#pragma unroll
  for (int mi = 0; mi < 4; ++mi)
#pragma unroll
    for (int ni = 0; ni < 4; ++ni) {
      int gn = n0 + wn + ni * 16 + col;
      float bv = bias[gn];
#pragma unroll
      for (int r = 0; r < 4; ++r) {
        int gm = m0 + wm + mi * 16 + quad * 4 + r;
        outp[(size_t)gm * N + gn] = acc[mi][ni][r] + bv;
      }
    }
}

// ---------------- attention v5: sized staging + XCD-grouped slots ----------------
// blockIdx = wi*256 + bh  ->  all 16 slots of one (b,h) share blockIdx%8 (same XCD L2).
// Staging sized to the segment: K stages jtc*16 rows; V stages jtcp*2 j-chunks per d.
__global__ __launch_bounds__(256) void attn_kernel(const unsigned short* __restrict__ qn,
                                                   const unsigned short* __restrict__ kn,
                                                   const unsigned short* __restrict__ vtb,
                                                   const float* __restrict__ slog,
                                                   unsigned short* __restrict__ outb) {
  __shared__ __align__(16) unsigned short Ks[128 * 64];   // chunk(row,cc) at row*8 + (cc^(row&7))
  __shared__ __align__(16) unsigned short Vs[64 * 128];   // chunk(d,jc)  at d*16 + (jc^(d&15))
  __shared__ __align__(16) unsigned short Ps[4 * 16 * 132];

  const int t = threadIdx.x;
  const int lane = t & 63, w = t >> 6;
  const int col = lane & 15, quad = lane >> 4;
  const int wi = blockIdx.x >> 8, bh = blockIdx.x & 255;
  const int h = bh & 15;
  const int seg = c_seg[wi];
  const int start = c_start2[seg], ln = c_len[seg], ps = c_ps[seg];
  const int njt = (ln + 15) >> 4;
  const int nchunk = (njt + 7) >> 3;
  const int qt = c_tile0[wi] + w;
  const bool qvalid = qt < njt;
  const float smul = __expf(fminf(slog[h], 4.6051701859880914f));

  // ---- Q fragment + in-register l2norm*scale ----
  const int qi = qt * 16 + col;
  const unsigned short* qrow = qn + ((size_t)bh * Ll + start + qi) * 64;
  bf16x8 qf0 = *reinterpret_cast<const bf16x8*>(qrow + quad * 8);
  bf16x8 qf1 = *reinterpret_cast<const bf16x8*>(qrow + 32 + quad * 8);
  {
    float ss = 0.f;
#pragma unroll
    for (int e = 0; e < 8; ++e) {
      float f0 = bf16_f32((unsigned short)qf0[e]), f1 = bf16_f32((unsigned short)qf1[e]);
      ss += f0 * f0 + f1 * f1;
    }
    ss += __shfl_xor(ss, 16);
    ss += __shfl_xor(ss, 32);
    const float qsc = smul / fmaxf(sqrtf(ss), 1e-12f);
#pragma unroll
    for (int e = 0; e < 8; ++e) {
      qf0[e] = (short)f32_bf16(bf16_f32((unsigned short)qf0[e]) * qsc);
      qf1[e] = (short)f32_bf16(bf16_f32((unsigned short)qf1[e]) * qsc);
    }
  }

  f32x4 o[4];
#pragma unroll
  for (int nt = 0; nt < 4; ++nt)
#pragma unroll
    for (int r = 0; r < 4; ++r) o[nt][r] = 0.f;
  float m4[4] = {-1e30f, -1e30f, -1e30f, -1e30f};
  float l4[4] = {0.f, 0.f, 0.f, 0.f};

  const int jc_t = (t & 15) ^ (t >> 4);   // thread-fixed V j-chunk

  for (int ch = 0; ch < nchunk; ++ch) {
    const int jbase = ch * 128;
    const int jtc = (njt - ch * 8 > 8) ? 8 : (njt - ch * 8);
    const int jtcp = (jtc + 1) & ~1;
    const int rowsK = jtc * 16;
    const int jcmax = jtcp * 2;
    __syncthreads();   // previous chunk's LDS reads done

    // ---- stage K rows (rowsK x 64d): chunk grid 128x8, rows >= rowsK skipped ----
#pragma unroll
    for (int i = 0; i < 4; ++i) {
      int c = i * 256 + w * 64 + lane;
      int jr = c >> 3;
      if (jr < rowsK) {
        int cc = (c & 7) ^ (jr & 7);
        async_copy16(kn + ((size_t)bh * Ll + start + jbase + jr) * 64 + cc * 8,
                     Ks + (i * 256 + w * 64) * 8);
      }
    }
    // ---- stage V^T (64d x jcmax*8 j): chunk grid 64x16, jc >= jcmax skipped ----
    if (jc_t < jcmax) {
#pragma unroll
      for (int i = 0; i < 4; ++i) {
        int d = i * 16 + (t >> 4);
        async_copy16(vtb + ((size_t)bh * 64 + d) * LPAD + ps + jbase + jc_t * 8,
                     Vs + (i * 256 + w * 64) * 8);
      }
    }
    __syncthreads();

    // ---- S = Q K^T ----
    f32x4 sf[8];
#pragma unroll
    for (int jt = 0; jt < 8; ++jt) {
      if (jt >= jtcp) continue;
      f32x4 s;
#pragma unroll
      for (int r = 0; r < 4; ++r) s[r] = 0.f;
      if (jt < jtc) {
        int jrow = jt * 16 + col;
        bf16x8 k0 = *reinterpret_cast<const bf16x8*>(&Ks[(jrow * 8 + (quad ^ (jrow & 7))) * 8]);
        bf16x8 k1 = *reinterpret_cast<const bf16x8*>(&Ks[(jrow * 8 + ((4 + quad) ^ (jrow & 7))) * 8]);
        s = __builtin_amdgcn_mfma_f32_16x16x32_bf16(qf0, k0, s, 0, 0, 0);
        s = __builtin_amdgcn_mfma_f32_16x16x32_bf16(qf1, k1, s, 0, 0, 0);
      }
      if (jbase + jt * 16 + col >= ln) {
#pragma unroll
        for (int r = 0; r < 4; ++r) s[r] = -1e30f;
      }
      sf[jt] = s;
    }
    // ---- online softmax ----
    float mc[4];
#pragma unroll
    for (int r = 0; r < 4; ++r) mc[r] = sf[0][r];
#pragma unroll
    for (int jt = 1; jt < 8; ++jt) {
      if (jt >= jtcp) continue;
#pragma unroll
      for (int r = 0; r < 4; ++r) mc[r] = fmaxf(mc[r], sf[jt][r]);
    }
#pragma unroll
    for (int mask = 1; mask <= 8; mask <<= 1)
#pragma unroll
      for (int r = 0; r < 4; ++r) mc[r] = fmaxf(mc[r], __shfl_xor(mc[r], mask));
    float alpha[4];
#pragma unroll
    for (int r = 0; r < 4; ++r) {
      float mn = fmaxf(m4[r], mc[r]);
      alpha[r] = __expf(m4[r] - mn);
      m4[r] = mn;
    }
    float ls[4] = {0.f, 0.f, 0.f, 0.f};
#pragma unroll
    for (int jt = 0; jt < 8; ++jt) {
      if (jt >= jtcp) continue;
#pragma unroll
      for (int r = 0; r < 4; ++r) {
        float pv = __expf(sf[jt][r] - m4[r]);
        ls[r] += pv;
        Ps[(w * 16 + quad * 4 + r) * 132 + jt * 16 + col] = f32_bf16(pv);
      }
    }
#pragma unroll
    for (int mask = 1; mask <= 8; mask <<= 1)
#pragma unroll
      for (int r = 0; r < 4; ++r) ls[r] += __shfl_xor(ls[r], mask);
#pragma unroll
    for (int r = 0; r < 4; ++r) l4[r] = l4[r] * alpha[r] + ls[r];
#pragma unroll
    for (int nt = 0; nt < 4; ++nt)
#pragma unroll
      for (int r = 0; r < 4; ++r) o[nt][r] *= alpha[r];

    // ---- O += P V ----
#pragma unroll
    for (int kk2 = 0; kk2 < 4; ++kk2) {
      if (kk2 >= (jtcp >> 1)) continue;
      bf16x8 pf = *reinterpret_cast<const bf16x8*>(&Ps[(w * 16 + col) * 132 + kk2 * 32 + quad * 8]);
#pragma unroll
      for (int nt = 0; nt < 4; ++nt) {
        int d = nt * 16 + col;
        int slot = (kk2 * 4 + quad) ^ (d & 15);
        bf16x8 vf = *reinterpret_cast<const bf16x8*>(&Vs[(d * 16 + slot) * 8]);
        o[nt] = __builtin_amdgcn_mfma_f32_16x16x32_bf16(pf, vf, o[nt], 0, 0, 0);
      }
    }
  }

  if (qvalid) {
    float inv[4];
#pragma unroll
    for (int r = 0; r < 4; ++r) inv[r] = 1.f / l4[r];
    const int b = bh >> 4;
#pragma unroll
    for (int nt = 0; nt < 4; ++nt)
#pragma unroll
      for (int r = 0; r < 4; ++r) {
        int ri = qt * 16 + quad * 4 + r;
        if (ri < ln) {
          size_t off = ((size_t)b * Ll + start + ri) * Cc + h * 64 + nt * 16 + col;
          outb[off] = f32_bf16(o[nt][r] * inv[r]);
        }
      }
  }
}

extern "C" void kernel_launch(void* const* d_in, const int* in_sizes, int n_in,
                              void* d_out, int out_size, void* d_ws, size_t ws_size,
                              hipStream_t stream) {
  const float* x     = (const float*)d_in[0];
  const float* wqkv  = (const float*)d_in[2];
  const float* qbias = (const float*)d_in[3];
  const float* vbias = (const float*)d_in[4];
  const float* slog  = (const float*)d_in[5];
  const float* wproj = (const float*)d_in[6];
  const float* pbias = (const float*)d_in[7];
  float* out = (float*)d_out;

  const size_t nX  = (size_t)Bb * Ll * Cc;      // 11,141,120
  const size_t nWq = (size_t)3 * Cc * Cc;       // 3,145,728
  const size_t nWp = (size_t)Cc * Cc;       // 1,048,576
  const size_t nVt = (size_t)Bb * Hh * 64 * LPAD;

  char* p = (char*)d_ws;
  unsigned short* xb     = (unsigned short*)p;  p += nX * 2;
  unsigned short* wqkvb  = (unsigned short*)p;  p += nWq * 2;
  unsigned short* wprojb = (unsigned short*)p;  p += nWp * 2;
  unsigned short* qn     = (unsigned short*)p;  p += nX * 2;
  unsigned short* kn     = (unsigned short*)p;  p += nX * 2;
  unsigned short* vtb    = (unsigned short*)p;  p += nVt * 2;
  unsigned short* attn   = xb;  // reuse: xb dead after gemm_qkv

  conv_kernel<<<(int)(nX / 1024), 256, 0, stream>>>(x, xb, (int)nX);
  conv_kernel<<<(int)(nWq / 1024), 256, 0, stream>>>(wqkv, wqkvb, (int)nWq);
  conv_kernel<<<(int)(nWp / 1024), 256, 0, stream>>>(wproj, wprojb, (int)nWp);

  gemm_qkv<<<dim3(12, 85), 512, 0, stream>>>(xb, wqkvb, qbias, vbias, qn, kn, vtb);
  attn_kernel<<<Bb * Hh * 16, 256, 0, stream>>>(qn, kn, vtb, slog, attn);
  gemm_bt<<<dim3(8, 85), 256, 0, stream>>>(attn, wprojb, pbias, out, 10880, 1024, 1024);
}

// Round 4
// 323.101 us; speedup vs baseline: 1.0404x; 1.0220x over previous
//
#include <hip/hip_runtime.h>

typedef __attribute__((ext_vector_type(8))) short bf16x8;
typedef __attribute__((ext_vector_type(4))) float f32x4;

#define Hh   16
#define Ll   680
#define Cc   1024
#define Bb   16
#define NSEG 10
#define LPAD 720   // padded per-segment V length (each segment start 8-aligned)

__device__ __forceinline__ unsigned short f32_bf16(float f) {
  union { float f; unsigned int u; } x; x.f = f;
  unsigned int r = x.u + 0x7FFFu + ((x.u >> 16) & 1u);   // RNE
  return (unsigned short)(r >> 16);
}
__device__ __forceinline__ float bf16_f32(unsigned short u) {
  union { unsigned int u; float f; } x; x.u = ((unsigned int)u) << 16;
  return x.f;
}

__device__ __forceinline__ void async_copy16(const unsigned short* g, unsigned short* l) {
  __builtin_amdgcn_global_load_lds(
      (const __attribute__((address_space(1))) unsigned int*)g,
      (__attribute__((address_space(3))) unsigned int*)l, 16, 0, 0);
}

// segment tables (patch_nums are compile-time constants)
__device__ __constant__ int c_start2[11] = {0,1,5,14,30,55,91,155,255,424,680};
__device__ __constant__ int c_ps[NSEG]   = {0,8,16,32,48,80,120,184,288,464};
__device__ __constant__ int c_seg[16]    = {0,1,2,3,4,5,6,7,7,8,8,8,9,9,9,9};
__device__ __constant__ int c_tile0[16]  = {0,0,0,0,0,0,0,0,4,0,4,8,0,4,8,12};
__device__ __constant__ int c_len[NSEG]  = {1,4,9,16,25,36,64,100,169,256};

// compile-time l -> padded-l table (kills the per-element segment search)
struct PlTab { unsigned short v[Ll]; };
constexpr PlTab make_pl() {
  PlTab t{};
  int starts[11] = {0,1,5,14,30,55,91,155,255,424,680};
  int ps[10]     = {0,8,16,32,48,80,120,184,288,464};
  for (int s = 0; s < 10; ++s)
    for (int l = starts[s]; l < starts[s + 1]; ++l)
      t.v[l] = (unsigned short)(l - starts[s] + ps[s]);
  return t;
}
__device__ __constant__ PlTab c_plt = make_pl();

// ---------------- elementwise f32 -> bf16 cast ----------------
__global__ __launch_bounds__(256) void conv_kernel(const float* __restrict__ src,
                                                   unsigned short* __restrict__ dst, int n) {
  int i = (blockIdx.x * 256 + threadIdx.x) * 4;
  if (i + 3 < n) {
    float4 v = *reinterpret_cast<const float4*>(src + i);
    ushort4 o;
    o.x = f32_bf16(v.x); o.y = f32_bf16(v.y); o.z = f32_bf16(v.z); o.w = f32_bf16(v.w);
    *reinterpret_cast<ushort4*>(dst + i) = o;
  }
}

// ---------------- QKV GEMM v4: 128x256 tile, half-tile ring pipeline ----------------
// T3+T4 proper: staging distributed INSIDE phases at half-tile granularity; counted
// vmcnt at every phase end (6/9), loads span 2-4 barriers; no monolithic drain.
// LDS ring: 3 bufs x {A: 2 halves of 64x64, B: 2 halves of 128x64} = 144KB.
// Wave's 64 output rows split 32+32 across the A-halves so phase p consumes only
// A-half p -> slots free mid-K-tile, ring is race-free (stage slot S only after the
// all-waves barrier that follows S's readers' lgkmcnt).
__global__ __launch_bounds__(512, 2) void gemm_qkv(const unsigned short* __restrict__ A,
                                                   const unsigned short* __restrict__ Bm,
                                                   const float* __restrict__ qb,
                                                   const float* __restrict__ vb,
                                                   unsigned short* __restrict__ qn,
                                                   unsigned short* __restrict__ kn,
                                                   unsigned short* __restrict__ vtb) {
  // A slots: 6 x 4096 shorts (48KB) at [0, 24576); B slots: 6 x 8192 shorts (96KB) after.
  __shared__ __align__(16) unsigned short lds[73728];
  const int t = threadIdx.x;
  const int lane = t & 63, w = t >> 6;
  const int col = lane & 15, quad = lane >> 4;
  const int wn = (w >> 1) * 64;
  const int m0 = blockIdx.y * 128, n0 = blockIdx.x * 256;
  const int bhs = wn >> 7;                       // wave's B half (0 or 1)

  // stage one A half-tile (64 rows x 64 k = 8KB): 1 load/thread
  auto stageA = [&](int d3, int hs, int k0) {
    int kc = k0 > 960 ? 960 : k0;                // tail clamp (staged-but-never-read)
    int r = t >> 3;                              // 0..63
    int part = (t & 7) ^ (r & 7);
    async_copy16(A + (size_t)(m0 + hs * 64 + r) * 1024 + kc + part * 8,
                 lds + (d3 * 2 + hs) * 4096 + w * 512);
  };
  // stage one B half-tile (128 rows x 64 k = 16KB): 2 loads/thread
  auto stageB = [&](int d3, int hs, int k0) {
    int kc = k0 > 960 ? 960 : k0;
#pragma unroll
    for (int i = 0; i < 2; ++i) {
      int c = i * 512 + t;
      int r = c >> 3;                            // 0..127
      int part = (c & 7) ^ (r & 7);
      async_copy16(Bm + (size_t)(n0 + hs * 128 + r) * 1024 + kc + part * 8,
                   lds + 24576 + (d3 * 2 + hs) * 8192 + (i * 512 + w * 64) * 8);
    }
  };

  f32x4 acc[4][4];
#pragma unroll
  for (int i = 0; i < 4; ++i)
#pragma unroll
    for (int j = 0; j < 4; ++j)
#pragma unroll
      for (int r = 0; r < 4; ++r) acc[i][j][r] = 0.f;

  // prologue: tiles 0,1 full + {Bh0,Ah0} of tile 2 = 15 loads/thread
#pragma unroll
  for (int tt = 0; tt < 2; ++tt) {
    stageB(tt, 0, tt * 64); stageA(tt, 0, tt * 64);
    stageB(tt, 1, tt * 64); stageA(tt, 1, tt * 64);
  }
  stageB(2, 0, 128); stageA(2, 0, 128);
  asm volatile("s_waitcnt vmcnt(9)" ::: "memory");   // tile 0 landed; 9 in flight
  __builtin_amdgcn_s_barrier();
  __builtin_amdgcn_sched_barrier(0);

  int bsel = 0;
  for (int tt = 0; tt < 16; ++tt) {
    const int b  = bsel;                          // this tile's buf
    const int b2 = (bsel + 2 >= 3) ? bsel - 1 : bsel + 2;   // (tt+2)%3
    const unsigned short* As0 = lds + (b * 2 + 0) * 4096;
    const unsigned short* As1 = lds + (b * 2 + 1) * 4096;
    const unsigned short* Bs  = lds + 24576 + (b * 2 + bhs) * 8192;
    bf16x8 bfr[4][2], af[2][2];

    // ===== phase 0: read B(all) + A-half0 frags; stage Bh1,Ah1(tt+2); 16 MFMA =====
#pragma unroll
    for (int nf = 0; nf < 4; ++nf) {
      int rb = (wn & 64) + nf * 16 + col;
#pragma unroll
      for (int kq = 0; kq < 2; ++kq)
        bfr[nf][kq] = *reinterpret_cast<const bf16x8*>(
            &Bs[(rb * 8 + ((kq * 4 + quad) ^ (col & 7))) * 8]);
    }
#pragma unroll
    for (int j = 0; j < 2; ++j) {
      int ri = (w & 1) * 32 + j * 16 + col;
#pragma unroll
      for (int kq = 0; kq < 2; ++kq)
        af[j][kq] = *reinterpret_cast<const bf16x8*>(
            &As0[(ri * 8 + ((kq * 4 + quad) ^ (col & 7))) * 8]);
    }
    stageB(b2, 1, (tt + 2) * 64);
    stageA(b2, 1, (tt + 2) * 64);
    __builtin_amdgcn_s_barrier();
    __builtin_amdgcn_s_setprio(1);
#pragma unroll
    for (int j = 0; j < 2; ++j)
#pragma unroll
      for (int nf = 0; nf < 4; ++nf)
#pragma unroll
        for (int kq = 0; kq < 2; ++kq)
          acc[j][nf] = __builtin_amdgcn_mfma_f32_16x16x32_bf16(af[j][kq], bfr[nf][kq],
                                                               acc[j][nf], 0, 0, 0);
    __builtin_amdgcn_s_setprio(0);
    __builtin_amdgcn_sched_barrier(0);
    asm volatile("s_waitcnt vmcnt(6)" ::: "memory");   // Ah1/Bh1(tt) landed for phase 1
    __builtin_amdgcn_s_barrier();
    __builtin_amdgcn_sched_barrier(0);

    // ===== phase 1: read A-half1 frags (B held in regs); stage Bh0,Ah0(tt+3); 16 MFMA =====
#pragma unroll
    for (int j = 0; j < 2; ++j) {
      int ri = (w & 1) * 32 + j * 16 + col;
#pragma unroll
      for (int kq = 0; kq < 2; ++kq)
        af[j][kq] = *reinterpret_cast<const bf16x8*>(
            &As1[(ri * 8 + ((kq * 4 + quad) ^ (col & 7))) * 8]);
    }
    stageB(b, 0, (tt + 3) * 64);                 // (tt+3)%3 == b; B(b)/Ah0(b) freed at ph0 bar
    stageA(b, 0, (tt + 3) * 64);
    __builtin_amdgcn_s_barrier();
    __builtin_amdgcn_s_setprio(1);
#pragma unroll
    for (int j = 0; j < 2; ++j)
#pragma unroll
      for (int nf = 0; nf < 4; ++nf)
#pragma unroll
        for (int kq = 0; kq < 2; ++kq)
          acc[2 + j][nf] = __builtin_amdgcn_mfma_f32_16x16x32_bf16(af[j][kq], bfr[nf][kq],
                                                                   acc[2 + j][nf], 0, 0, 0);
    __builtin_amdgcn_s_setprio(0);
    __builtin_amdgcn_sched_barrier(0);
    asm volatile("s_waitcnt vmcnt(9)" ::: "memory");   // B/Ah0(tt+1) landed for next ph0
    __builtin_amdgcn_s_barrier();
    __builtin_amdgcn_sched_barrier(0);

    bsel = (bsel == 2) ? 0 : bsel + 1;
  }

  // ---- fused epilogue (same algebra; row mapping remapped for the half-split) ----
  const int nbase = n0 + wn;
  const int field = nbase >> 10;          // wave-uniform
  const int h = (nbase >> 6) & 15;

  if (field < 2) {
    float scl[4][4];
    if (field == 1) {                     // k: per-row 1/||k|| across the 16 col-lanes
#pragma unroll
      for (int mi = 0; mi < 4; ++mi)
#pragma unroll
        for (int r = 0; r < 4; ++r) {
          float s = 0.f;
#pragma unroll
          for (int ni = 0; ni < 4; ++ni) s += acc[mi][ni][r] * acc[mi][ni][r];
          s += __shfl_xor(s, 1); s += __shfl_xor(s, 2);
          s += __shfl_xor(s, 4); s += __shfl_xor(s, 8);
          scl[mi][r] = 1.f / fmaxf(sqrtf(s), 1e-12f);
        }
    }
    unsigned short* dst0 = (field == 0) ? qn : kn;
#pragma unroll
    for (int ni = 0; ni < 4; ++ni) {
      const int d = ni * 16 + col;
      const float bv = (field == 0) ? qb[h * 64 + d] : 0.f;
#pragma unroll
      for (int mi = 0; mi < 4; ++mi)
#pragma unroll
        for (int r = 0; r < 4; ++r) {
          int gm = m0 + (mi >> 1) * 64 + (w & 1) * 32 + (mi & 1) * 16 + quad * 4 + r;
          int b = gm / 680, l = gm - b * 680;
          float v = (field == 0) ? (acc[mi][ni][r] + bv) : (acc[mi][ni][r] * scl[mi][r]);
          dst0[((size_t)(b * Hh + h) * Ll + l) * 64 + d] = f32_bf16(v);
        }
    }
  } else {                                // v: transposed, segment-padded (table lookup)
#pragma unroll
    for (int mi = 0; mi < 4; ++mi) {
      int pl4[4], bb4[4];
#pragma unroll
      for (int r = 0; r < 4; ++r) {
        int gm = m0 + (mi >> 1) * 64 + (w & 1) * 32 + (mi & 1) * 16 + quad * 4 + r;
        int b = gm / 680, l = gm - b * 680;
        pl4[r] = c_plt.v[l];
        bb4[r] = b;
      }
#pragma unroll
      for (int ni = 0; ni < 4; ++ni) {
        const int d = ni * 16 + col;
        const float bv = vb[h * 64 + d];
#pragma unroll
        for (int r = 0; r < 4; ++r)
          vtb[((size_t)(bb4[r] * Hh + h) * 64 + d) * LPAD + pl4[r]] =
              f32_bf16(acc[mi][ni][r] + bv);
      }
    }
  }
}

// ---------------- plain B^T GEMM (proj), f32 out ----------------
__global__ __launch_bounds__(256) void gemm_bt(const unsigned short* __restrict__ A,
                                               const unsigned short* __restrict__ Bm,
                                               const float* __restrict__ bias,
                                               float* __restrict__ outp,
                                               int M, int N, int K) {
  __shared__ __align__(16) unsigned short As[128 * 64];
  __shared__ __align__(16) unsigned short Bs[128 * 64];
  const int t = threadIdx.x;
  const int lane = t & 63, w = t >> 6;
  const int col = lane & 15, quad = lane >> 4;
  const int wm = (w & 1) * 64, wn = (w >> 1) * 64;
  const int m0 = blockIdx.y * 128, n0 = blockIdx.x * 128;

  f32x4 acc[4][4];
#pragma unroll
  for (int i = 0; i < 4; ++i)
#pragma unroll
    for (int j = 0; j < 4; ++j)
#pragma unroll
      for (int r = 0; r < 4; ++r) acc[i][j][r] = 0.f;

  const int cbase = w * 256 + lane;
  for (int k0 = 0; k0 < K; k0 += 64) {
    __syncthreads();
#pragma unroll
    for (int i = 0; i < 4; ++i) {
      int c = cbase + i * 64;
      int r = c >> 3;
      int part = (c & 7) ^ (r & 7);
      async_copy16(A + (size_t)(m0 + r) * K + k0 + part * 8, As + (w * 256 + i * 64) * 8);
      async_copy16(Bm + (size_t)(n0 + r) * K + k0 + part * 8, Bs + (w * 256 + i * 64) * 8);
    }
    __syncthreads();
#pragma unroll
    for (int kk = 0; kk < 64; kk += 32) {
      const int p = (kk >> 3) + quad;
      bf16x8 af[4], bfr[4];
#pragma unroll
      for (int mi = 0; mi < 4; ++mi) {
        int row = wm + mi * 16 + col;
        af[mi] = *reinterpret_cast<const bf16x8*>(&As[(row * 8 + (p ^ (col & 7))) * 8]);
      }
#pragma unroll
      for (int ni = 0; ni < 4; ++ni) {
        int row = wn + ni * 16 + col;
        bfr[ni] = *reinterpret_cast<const bf16x8*>(&Bs[(row * 8 + (p ^ (col & 7))) * 8]);
      }
#pragma unroll
      for (int mi = 0; mi < 4; ++mi)
#pragma unroll
        for (int ni = 0; ni < 4; ++ni)
          acc[mi][ni] = __builtin_amdgcn_mfma_f32_16x16x32_bf16(af[mi], bfr[ni], acc[mi][ni], 0, 0, 0);
    }
  }
#pragma unroll
  for (int mi = 0; mi < 4; ++mi)
#pragma unroll
    for (int ni = 0; ni < 4; ++ni) {
      int gn = n0 + wn + ni * 16 + col;
      float bv = bias[gn];
#pragma unroll
      for (int r = 0; r < 4; ++r) {
        int gm = m0 + wm + mi * 16 + quad * 4 + r;
        outp[(size_t)gm * N + gn] = acc[mi][ni][r] + bv;
      }
    }
}

// ---------------- attention v5: sized staging + XCD-grouped slots ----------------
// blockIdx = wi*256 + bh  ->  all 16 slots of one (b,h) share blockIdx%8 (same XCD L2).
// Staging sized to the segment: K stages jtc*16 rows; V stages jtcp*2 j-chunks per d.
__global__ __launch_bounds__(256) void attn_kernel(const unsigned short* __restrict__ qn,
                                                   const unsigned short* __restrict__ kn,
                                                   const unsigned short* __restrict__ vtb,
                                                   const float* __restrict__ slog,
                                                   unsigned short* __restrict__ outb) {
  __shared__ __align__(16) unsigned short Ks[128 * 64];   // chunk(row,cc) at row*8 + (cc^(row&7))
  __shared__ __align__(16) unsigned short Vs[64 * 128];   // chunk(d,jc)  at d*16 + (jc^(d&15))
  __shared__ __align__(16) unsigned short Ps[4 * 16 * 132];

  const int t = threadIdx.x;
  const int lane = t & 63, w = t >> 6;
  const int col = lane & 15, quad = lane >> 4;
  const int wi = blockIdx.x >> 8, bh = blockIdx.x & 255;
  const int h = bh & 15;
  const int seg = c_seg[wi];
  const int start = c_start2[seg], ln = c_len[seg], ps = c_ps[seg];
  const int njt = (ln + 15) >> 4;
  const int nchunk = (njt + 7) >> 3;
  const int qt = c_tile0[wi] + w;
  const bool qvalid = qt < njt;
  const float smul = __expf(fminf(slog[h], 4.6051701859880914f));

  // ---- Q fragment + in-register l2norm*scale ----
  const int qi = qt * 16 + col;
  const unsigned short* qrow = qn + ((size_t)bh * Ll + start + qi) * 64;
  bf16x8 qf0 = *reinterpret_cast<const bf16x8*>(qrow + quad * 8);
  bf16x8 qf1 = *reinterpret_cast<const bf16x8*>(qrow + 32 + quad * 8);
  {
    float ss = 0.f;
#pragma unroll
    for (int e = 0; e < 8; ++e) {
      float f0 = bf16_f32((unsigned short)qf0[e]), f1 = bf16_f32((unsigned short)qf1[e]);
      ss += f0 * f0 + f1 * f1;
    }
    ss += __shfl_xor(ss, 16);
    ss += __shfl_xor(ss, 32);
    const float qsc = smul / fmaxf(sqrtf(ss), 1e-12f);
#pragma unroll
    for (int e = 0; e < 8; ++e) {
      qf0[e] = (short)f32_bf16(bf16_f32((unsigned short)qf0[e]) * qsc);
      qf1[e] = (short)f32_bf16(bf16_f32((unsigned short)qf1[e]) * qsc);
    }
  }

  f32x4 o[4];
#pragma unroll
  for (int nt = 0; nt < 4; ++nt)
#pragma unroll
    for (int r = 0; r < 4; ++r) o[nt][r] = 0.f;
  float m4[4] = {-1e30f, -1e30f, -1e30f, -1e30f};
  float l4[4] = {0.f, 0.f, 0.f, 0.f};

  const int jc_t = (t & 15) ^ (t >> 4);   // thread-fixed V j-chunk

  for (int ch = 0; ch < nchunk; ++ch) {
    const int jbase = ch * 128;
    const int jtc = (njt - ch * 8 > 8) ? 8 : (njt - ch * 8);
    const int jtcp = (jtc + 1) & ~1;
    const int rowsK = jtc * 16;
    const int jcmax = jtcp * 2;
    __syncthreads();   // previous chunk's LDS reads done

    // ---- stage K rows (rowsK x 64d): chunk grid 128x8, rows >= rowsK skipped ----
#pragma unroll
    for (int i = 0; i < 4; ++i) {
      int c = i * 256 + w * 64 + lane;
      int jr = c >> 3;
      if (jr < rowsK) {
        int cc = (c & 7) ^ (jr & 7);
        async_copy16(kn + ((size_t)bh * Ll + start + jbase + jr) * 64 + cc * 8,
                     Ks + (i * 256 + w * 64) * 8);
      }
    }
    // ---- stage V^T (64d x jcmax*8 j): chunk grid 64x16, jc >= jcmax skipped ----
    if (jc_t < jcmax) {
#pragma unroll
      for (int i = 0; i < 4; ++i) {
        int d = i * 16 + (t >> 4);
        async_copy16(vtb + ((size_t)bh * 64 + d) * LPAD + ps + jbase + jc_t * 8,
                     Vs + (i * 256 + w * 64) * 8);
      }
    }
    __syncthreads();

    // ---- S = Q K^T ----
    f32x4 sf[8];
#pragma unroll
    for (int jt = 0; jt < 8; ++jt) {
      if (jt >= jtcp) continue;
      f32x4 s;
#pragma unroll
      for (int r = 0; r < 4; ++r) s[r] = 0.f;
      if (jt < jtc) {
        int jrow = jt * 16 + col;
        bf16x8 k0 = *reinterpret_cast<const bf16x8*>(&Ks[(jrow * 8 + (quad ^ (jrow & 7))) * 8]);
        bf16x8 k1 = *reinterpret_cast<const bf16x8*>(&Ks[(jrow * 8 + ((4 + quad) ^ (jrow & 7))) * 8]);
        s = __builtin_amdgcn_mfma_f32_16x16x32_bf16(qf0, k0, s, 0, 0, 0);
        s = __builtin_amdgcn_mfma_f32_16x16x32_bf16(qf1, k1, s, 0, 0, 0);
      }
      if (jbase + jt * 16 + col >= ln) {
#pragma unroll
        for (int r = 0; r < 4; ++r) s[r] = -1e30f;
      }
      sf[jt] = s;
    }
    // ---- online softmax ----
    float mc[4];
#pragma unroll
    for (int r = 0; r < 4; ++r) mc[r] = sf[0][r];
#pragma unroll
    for (int jt = 1; jt < 8; ++jt) {
      if (jt >= jtcp) continue;
#pragma unroll
      for (int r = 0; r < 4; ++r) mc[r] = fmaxf(mc[r], sf[jt][r]);
    }
#pragma unroll
    for (int mask = 1; mask <= 8; mask <<= 1)
#pragma unroll
      for (int r = 0; r < 4; ++r) mc[r] = fmaxf(mc[r], __shfl_xor(mc[r], mask));
    float alpha[4];
#pragma unroll
    for (int r = 0; r < 4; ++r) {
      float mn = fmaxf(m4[r], mc[r]);
      alpha[r] = __expf(m4[r] - mn);
      m4[r] = mn;
    }
    float ls[4] = {0.f, 0.f, 0.f, 0.f};
#pragma unroll
    for (int jt = 0; jt < 8; ++jt) {
      if (jt >= jtcp) continue;
#pragma unroll
      for (int r = 0; r < 4; ++r) {
        float pv = __expf(sf[jt][r] - m4[r]);
        ls[r] += pv;
        Ps[(w * 16 + quad * 4 + r) * 132 + jt * 16 + col] = f32_bf16(pv);
      }
    }
#pragma unroll
    for (int mask = 1; mask <= 8; mask <<= 1)
#pragma unroll
      for (int r = 0; r < 4; ++r) ls[r] += __shfl_xor(ls[r], mask);
#pragma unroll
    for (int r = 0; r < 4; ++r) l4[r] = l4[r] * alpha[r] + ls[r];
#pragma unroll
    for (int nt = 0; nt < 4; ++nt)
#pragma unroll
      for (int r = 0; r < 4; ++r) o[nt][r] *= alpha[r];

    // ---- O += P V ----
#pragma unroll
    for (int kk2 = 0; kk2 < 4; ++kk2) {
      if (kk2 >= (jtcp >> 1)) continue;
      bf16x8 pf = *reinterpret_cast<const bf16x8*>(&Ps[(w * 16 + col) * 132 + kk2 * 32 + quad * 8]);
#pragma unroll
      for (int nt = 0; nt < 4; ++nt) {
        int d = nt * 16 + col;
        int slot = (kk2 * 4 + quad) ^ (d & 15);
        bf16x8 vf = *reinterpret_cast<const bf16x8*>(&Vs[(d * 16 + slot) * 8]);
        o[nt] = __builtin_amdgcn_mfma_f32_16x16x32_bf16(pf, vf, o[nt], 0, 0, 0);
      }
    }
  }

  if (qvalid) {
    float inv[4];
#pragma unroll
    for (int r = 0; r < 4; ++r) inv[r] = 1.f / l4[r];
    const int b = bh >> 4;
#pragma unroll
    for (int nt = 0; nt < 4; ++nt)
#pragma unroll
      for (int r = 0; r < 4; ++r) {
        int ri = qt * 16 + quad * 4 + r;
        if (ri < ln) {
          size_t off = ((size_t)b * Ll + start + ri) * Cc + h * 64 + nt * 16 + col;
          outb[off] = f32_bf16(o[nt][r] * inv[r]);
        }
      }
  }
}

extern "C" void kernel_launch(void* const* d_in, const int* in_sizes, int n_in,
                              void* d_out, int out_size, void* d_ws, size_t ws_size,
                              hipStream_t stream) {
  const float* x     = (const float*)d_in[0];
  const float* wqkv  = (const float*)d_in[2];
  const float* qbias = (const float*)d_in[3];
  const float* vbias = (const float*)d_in[4];
  const float* slog  = (const float*)d_in[5];
  const float* wproj = (const float*)d_in[6];
  const float* pbias = (const float*)d_in[7];
  float* out = (float*)d_out;

  const size_t nX  = (size_t)Bb * Ll * Cc;      // 11,141,120
  const size_t nWq = (size_t)3 * Cc * Cc;       // 3,145,728
  const size_t nWp = (size_t)Cc * Cc;           // 1,048,576
  const size_t nVt = (size_t)Bb * Hh * 64 * LPAD;

  char* p = (char*)d_ws;
  unsigned short* xb     = (unsigned short*)p;  p += nX * 2;
  unsigned short* wqkvb  = (unsigned short*)p;  p += nWq * 2;
  unsigned short* wprojb = (unsigned short*)p;  p += nWp * 2;
  unsigned short* qn     = (unsigned short*)p;  p += nX * 2;
  unsigned short* kn     = (unsigned short*)p;  p += nX * 2;
  unsigned short* vtb    = (unsigned short*)p;  p += nVt * 2;
  unsigned short* attn   = xb;  // reuse: xb dead after gemm_qkv

  conv_kernel<<<(int)(nX / 1024), 256, 0, stream>>>(x, xb, (int)nX);
  conv_kernel<<<(int)(nWq / 1024), 256, 0, stream>>>(wqkv, wqkvb, (int)nWq);
  conv_kernel<<<(int)(nWp / 1024), 256, 0, stream>>>(wproj, wprojb, (int)nWp);

  gemm_qkv<<<dim3(12, 85), 512, 0, stream>>>(xb, wqkvb, qbias, vbias, qn, kn, vtb);
  attn_kernel<<<Bb * Hh * 16, 256, 0, stream>>>(qn, kn, vtb, slog, attn);
  gemm_bt<<<dim3(8, 85), 256, 0, stream>>>(attn, wprojb, pbias, out, 10880, 1024, 1024);
}